// Round 10
// baseline (107.340 us; speedup 1.0000x reference)
//
#include <hip/hip_runtime.h>
#include <math.h>

#define NCLS 81
#define A_ANCH 8732
#define B_BATCH 64
#define NANCH (B_BATCH * A_ANCH)   // 558,848 anchors
#define EPSF 1e-7f

// ---- fused kernel geometry ----
#define TILE 8
#define TDW  (TILE * NCLS)      // 648 dwords/tile
#define BUFDW 768               // 3*256 staged dwords (120-dw over-read into pad)
#define WPB 8                   // waves per block
#define BLK (WPB * 64)          // 512 threads
#define GRIDB 768               // 3 blocks/CU * 256 CU -> ALL co-resident (barrier-safe)
#define NWAVES (GRIDB * WPB)    // 6144 wave pipelines
#define NT (NANCH / TILE)       // 69,856 tiles (exact)
#define MW 512                  // mine waves (blocks 0..63) get short quota
#define QM 9                    // their tile quota; see wave_run()

#define VPT 18                  // mine: 512*18 = 9216 >= 8732

// ---------------- workspace layout ----------------
// [0]        sout : NANCH floats (-logp0 per anchor)
// [SBYTES]   accum: 2 doubles | +16 hits(ull) | +24 pad | +32 ctr(u32) | +36 ctr2(u32)
static const size_t SBYTES = (size_t)NANCH * sizeof(float);

#define GLOAD_LDS16(g, l) __builtin_amdgcn_global_load_lds( \
    (const __attribute__((address_space(1))) void*)(g),      \
    (__attribute__((address_space(3))) void*)(l), 16, 0, 0)

__device__ __forceinline__ void stage_tile(const float* __restrict__ g,
                                           float* lb, int ln) {
    #pragma unroll
    for (int c = 0; c < 3; ++c) {
        GLOAD_LDS16(g + c * 256 + ln * 4, lb + c * 256);
    }
}

// contiguous run [S,E) per wave; waves 0..511 (mine blocks) get 9 tiles,
// 3296 waves get 12, 2336 get 11:  512*9 + 3296*12 + 2336*11 = 69,856 = NT
__device__ __forceinline__ void wave_run(int w, int& S, int& E) {
    int s, q;
    if (w < MW)            { q = 9;  s = 9 * w; }
    else if (w < MW + 3296){ q = 12; s = 4608 + 12 * (w - MW); }
    else                   { q = 11; s = 44160 + 11 * (w - MW - 3296); }
    S = s; E = s + q;
}

// ---------------- fused: lse -> grid barrier -> mine -> finalize ----------------
__global__ __launch_bounds__(BLK, 6) void ssd_fused_kernel(
    const float* __restrict__ conf, const float* __restrict__ loc,
    const float* __restrict__ tgt, float* __restrict__ sout,
    double* __restrict__ accum, unsigned long long* __restrict__ hits,
    unsigned int* __restrict__ ctr, unsigned int* __restrict__ ctr2,
    float* __restrict__ out)
{
    __shared__ float sb[WPB][2][BUFDW];   // 48 KB
    __shared__ int   cnt[34];
    __shared__ float fs[4];               // 0: sall, 1: sg, 2: pos_ce_corr, 3: pos_loc
    __shared__ int   nm_s;

    int tid = threadIdx.x;
    int wv = tid >> 6, ln = tid & 63;
    int bid = blockIdx.x;
    int w = bid * WPB + wv;
    int a = ln >> 3, l = ln & 7;          // 8 lanes/anchor

    // ---------------- phase A: lse over contiguous tile run ----------------
    int S, E; wave_run(w, S, E);
    stage_tile(conf + (size_t)S * TDW, &sb[wv][0][0], ln);
    int par = 0;

    #pragma clang loop unroll(disable)
    for (int t = S; t < E; ++t) {
        bool more = (t + 1 < E);
        if (more) stage_tile(conf + (size_t)(t + 1) * TDW, &sb[wv][par ^ 1][0], ln);

        // queue old->new: [stage(t) x3, store(t-1), stage(t+1) x3]; vmcnt(3)
        // retires all but the newest 3 => tile t landed, t+1 stays in flight.
        if (more) { asm volatile("s_waitcnt vmcnt(3)" ::: "memory"); }
        else      { asm volatile("s_waitcnt vmcnt(0)" ::: "memory"); }
        __builtin_amdgcn_sched_barrier(0);

        const float* r = &sb[wv][par][a * 81 + l * 10];
        float x0 = r[0];
        float e0 = 0.f, e1 = 0.f;
        #pragma unroll
        for (int j = 0; j < 10; j += 2) {
            e0 += __expf(r[j]);
            e1 += __expf(r[j + 1]);
        }
        float s = e0 + e1;
        if (l == 7) s += __expf(r[10]);   // class 80
        s += __shfl_xor(s, 1);
        s += __shfl_xor(s, 2);
        s += __shfl_xor(s, 4);
        if (l == 0) sout[(size_t)t * TILE + a] = __logf(s) - x0;  // -logp0 > 0

        par ^= 1;
    }

    bool miner = (bid < B_BATCH);
    size_t base = (size_t)bid * A_ANCH;
    unsigned posmask = 0u;
    float corr = 0.f, ploc = 0.f; int pc = 0;

    // ---------------- phase B0 (mine blocks): sout-independent precompute ----------------
    // Runs while other blocks are still streaming lse (mine waves had short quota).
    if (miner) {
        if (tid < 34) cnt[tid] = 0;
        if (tid < 4)  fs[tid] = 0.f;
        if (tid == 0) nm_s = 0;
        #pragma unroll
        for (int i = 0; i < VPT; ++i) {
            int idx = tid + i * BLK;
            int lab = (idx < A_ANCH) ? (int)tgt[(base + idx) * 5 + 4] : 0;
            if (lab > 0) {
                posmask |= (1u << i);
                size_t gi = base + idx;
                corr += conf[gi * NCLS] - conf[gi * NCLS + lab];   // r0 - r[label]
                float4 p = *(const float4*)(loc + gi * 4);
                const float* tg = tgt + gi * 5;
                float tx1 = tg[0], ty1 = tg[1], tx2 = tg[2], ty2 = tg[3];
                float area_p = (p.z - p.x) * (p.w - p.y);
                float area_t = (tx2 - tx1) * (ty2 - ty1);
                float iw = fmaxf(fminf(p.z, tx2) - fmaxf(p.x, tx1), 0.f);
                float ih = fmaxf(fminf(p.w, ty2) - fmaxf(p.y, ty1), 0.f);
                float inter = iw * ih;
                float uni   = area_p + area_t - inter;
                float iou   = inter / (uni + EPSF);
                float cw = fmaxf(p.z, tx2) - fminf(p.x, tx1);
                float ch = fmaxf(p.w, ty2) - fminf(p.y, ty1);
                float area_c = cw * ch;
                ploc += 1.f - (iou - (area_c - uni) / (area_c + EPSF));
                pc++;
            }
        }
        int lane = tid & 63;
        float lcorr = corr, lploc = ploc; int lpc = pc;
        for (int off = 32; off; off >>= 1) {
            lpc   += __shfl_xor(lpc, off);
            lcorr += __shfl_xor(lcorr, off);
            lploc += __shfl_xor(lploc, off);
        }
        __syncthreads();   // cnt/fs/nm_s init visible
        if (lane == 0) {
            if (lpc) atomicAdd(&nm_s, lpc);
            atomicAdd(&fs[2], lcorr);
            atomicAdd(&fs[3], lploc);
        }
    }

    // ---------------- grid barrier (all 768 blocks co-resident) ----------------
    __syncthreads();
    if (tid == 0) {
        __threadfence();   // release: sout stores visible at agent scope
        __hip_atomic_fetch_add(ctr, 1u, __ATOMIC_ACQ_REL, __HIP_MEMORY_SCOPE_AGENT);
    }
    if (!miner) return;
    if (tid == 0) {
        while (__hip_atomic_load(ctr, __ATOMIC_ACQUIRE, __HIP_MEMORY_SCOPE_AGENT) < GRIDB) {
            __builtin_amdgcn_s_sleep(1);
        }
    }
    __syncthreads();       // all threads see barrier passed

    // ---------------- phase B1: mining on sout ----------------
    float v[VPT];
    float pce_v = 0.f;
    #pragma unroll
    for (int i = 0; i < VPT; ++i) {
        int idx = tid + i * BLK;
        v[i] = (idx < A_ANCH) ? sout[base + idx] : -1.f;
        if (posmask & (1u << i)) { pce_v += v[i]; v[i] = -1.f; }  // positive: move to CE, mask
    }
    int lane = tid & 63;
    int c = 0; float sa = 0.f;
    #pragma unroll
    for (int i = 0; i < VPT; ++i) { if (v[i] >= 0.f) { c++; sa += v[i]; } }
    float lpce = pce_v;
    for (int off = 32; off; off >>= 1) {
        c += __shfl_xor(c, off); sa += __shfl_xor(sa, off); lpce += __shfl_xor(lpce, off);
    }
    if (lane == 0) { atomicAdd(&cnt[32], c); atomicAdd(&fs[0], sa); atomicAdd(&fs[2], lpce); }
    __syncthreads();

    int k = 3 * nm_s;
    int c0 = cnt[32]; float sall = fs[0];
    float negl = 0.f;
    if (k >= c0) {
        negl = sall;
    } else if (k > 0) {
        unsigned lo = 0u, hi = 0x7F800000u;
        int it = 0;
        while (hi - lo > 1u) {            // 31 uniform iterations
            unsigned mid = lo + (hi - lo) / 2u;
            float thr = __uint_as_float(mid);
            int cc = 0;
            #pragma unroll
            for (int i = 0; i < VPT; ++i) cc += (v[i] >= thr) ? 1 : 0;
            for (int off = 32; off; off >>= 1) cc += __shfl_xor(cc, off);
            if (lane == 0) atomicAdd(&cnt[it], cc);
            __syncthreads();
            if (cnt[it] >= k) lo = mid; else hi = mid;
            ++it;
        }
        float tth = __uint_as_float(lo);  // exact k-th largest value
        int cg = 0; float sg = 0.f;
        #pragma unroll
        for (int i = 0; i < VPT; ++i) { if (v[i] > tth) { cg++; sg += v[i]; } }
        for (int off = 32; off; off >>= 1) { cg += __shfl_xor(cg, off); sg += __shfl_xor(sg, off); }
        if (lane == 0) { atomicAdd(&cnt[33], cg); atomicAdd(&fs[1], sg); }
        __syncthreads();
        negl = fs[1] + (float)(k - cnt[33]) * tth;
    }

    // ---------------- per-batch accumulate + last-block finalize ----------------
    if (tid == 0) {
        atomicAdd(&accum[0], (double)(fs[2] + negl));
        atomicAdd(&accum[1], (double)fs[3]);
        atomicAdd(hits, (unsigned long long)nm_s);
        __threadfence();
        unsigned old = __hip_atomic_fetch_add(ctr2, 1u, __ATOMIC_ACQ_REL, __HIP_MEMORY_SCOPE_AGENT);
        if (old == B_BATCH - 1) {   // last miner: all adds are visible
            double conf_s = __hip_atomic_load(&accum[0], __ATOMIC_ACQUIRE, __HIP_MEMORY_SCOPE_AGENT);
            double loc_s  = __hip_atomic_load(&accum[1], __ATOMIC_ACQUIRE, __HIP_MEMORY_SCOPE_AGENT);
            unsigned long long h = __hip_atomic_load(hits, __ATOMIC_ACQUIRE, __HIP_MEMORY_SCOPE_AGENT);
            double denom = (double)(h > 0 ? h : 1ull);
            if (h > 0) {
                out[0] = (float)((conf_s + loc_s) / denom);
                out[1] = (float)(conf_s / denom);
                out[2] = (float)(loc_s / denom);
            } else {
                out[0] = 0.f; out[1] = 0.f; out[2] = 0.f;
            }
        }
    }
}

extern "C" void kernel_launch(void* const* d_in, const int* in_sizes, int n_in,
                              void* d_out, int out_size, void* d_ws, size_t ws_size,
                              hipStream_t stream) {
    const float* conf = (const float*)d_in[0];
    const float* loc  = (const float*)d_in[1];
    const float* tgt  = (const float*)d_in[2];
    float* out = (float*)d_out;

    char* ws = (char*)d_ws;
    float* sout = (float*)ws;
    double* accum = (double*)(ws + SBYTES);
    unsigned long long* hits = (unsigned long long*)(ws + SBYTES + 16);
    unsigned int* ctr  = (unsigned int*)(ws + SBYTES + 32);
    unsigned int* ctr2 = (unsigned int*)(ws + SBYTES + 36);

    // zero accum/hits/ctrs every call (graph-capturable)
    hipMemsetAsync(ws + SBYTES, 0, 64, stream);

    ssd_fused_kernel<<<dim3(GRIDB), dim3(BLK), 0, stream>>>(
        conf, loc, tgt, sout, accum, hits, ctr, ctr2, out);
}

// Round 11
// 62.911 us; speedup vs baseline: 1.7062x; 1.7062x over previous
//
#include <hip/hip_runtime.h>
#include <math.h>

#define NCLS 81
#define A_ANCH 8732
#define B_BATCH 64
#define NANCH (B_BATCH * A_ANCH)   // 558,848 anchors
#define EPSF 1e-7f

// ---- K1 tiling: 32 anchors/tile, register-staged, double-buffered LDS ----
#define TILE 32
#define TDW  (TILE * NCLS)      // 2592 dwords = 10368 B, 16B-aligned per tile
#define BUFDW 2624              // 10*256 + 64 (tail chunk region)
#define NT (NANCH / TILE)       // 17,464 tiles (exact)
#define GRID1 1792              // 7 blocks/CU * 256 CU (2x2624x4 = 21KB LDS/block)

// ---------------- workspace layout ----------------
// [0]      sout : NANCH floats (-logp0 per anchor)
// [SBYTES] accum: 2 doubles | +16 hits(ull) | +24 done-ctr(u32)
static const size_t SBYTES = (size_t)NANCH * sizeof(float);

// ---------------- K1: streaming -logp0 (lse - x0) per anchor ----------------
// Register path: 10x lane-contiguous global_load_dwordx4 (1 KB/instr) +
// guarded 32-dword tail -> named VGPRs -> ds_write_b128 into the other LDS
// buffer. Loads for tile t+1 issue BEFORE the compute on tile t; the
// compiler's auto s_waitcnt vmcnt(0) before the ds_write is the pipeline
// wait, covered by the compute phase + 7-wave/CU TLP.  [unchanged from R8]
__global__ __launch_bounds__(64) void lse_kernel(
    const float* __restrict__ conf, float* __restrict__ sout,
    double* __restrict__ accum, unsigned long long* __restrict__ hits,
    unsigned int* __restrict__ done)
{
    __shared__ float sb[2][BUFDW];   // 20,992 B -> 7 blocks/CU

    int tid = threadIdx.x;
    if (blockIdx.x == 0 && tid == 0) {   // consumers run in the next kernel
        accum[0] = 0.0; accum[1] = 0.0; *hits = 0ull; *done = 0u;
    }

    int a = tid & 31, h = tid >> 5;  // 2 lanes/anchor: h=0 -> cls 0..39, h=1 -> 40..80
    int t = blockIdx.x;

    float4 q0, q1, q2, q3, q4, q5, q6, q7, q8, q9;
    float qt = 0.f;

    // prologue: load tile t -> regs -> LDS[0]
    {
        const float4* p = (const float4*)conf + (size_t)t * (TDW / 4);
        q0 = p[0 * 64 + tid]; q1 = p[1 * 64 + tid]; q2 = p[2 * 64 + tid];
        q3 = p[3 * 64 + tid]; q4 = p[4 * 64 + tid]; q5 = p[5 * 64 + tid];
        q6 = p[6 * 64 + tid]; q7 = p[7 * 64 + tid]; q8 = p[8 * 64 + tid];
        q9 = p[9 * 64 + tid];
        if (tid < 32) qt = conf[(size_t)t * TDW + 2560 + tid];
        float4* lp = (float4*)&sb[0][0];
        lp[0 * 64 + tid] = q0; lp[1 * 64 + tid] = q1; lp[2 * 64 + tid] = q2;
        lp[3 * 64 + tid] = q3; lp[4 * 64 + tid] = q4; lp[5 * 64 + tid] = q5;
        lp[6 * 64 + tid] = q6; lp[7 * 64 + tid] = q7; lp[8 * 64 + tid] = q8;
        lp[9 * 64 + tid] = q9;
        if (tid < 32) sb[0][2560 + tid] = qt;
    }
    int par = 0;

    #pragma clang loop unroll(disable)
    while (true) {
        int tn = t + GRID1;
        bool more = (tn < NT);
        if (more) {   // issue next tile's loads; they fly during the compute below
            const float4* p = (const float4*)conf + (size_t)tn * (TDW / 4);
            q0 = p[0 * 64 + tid]; q1 = p[1 * 64 + tid]; q2 = p[2 * 64 + tid];
            q3 = p[3 * 64 + tid]; q4 = p[4 * 64 + tid]; q5 = p[5 * 64 + tid];
            q6 = p[6 * 64 + tid]; q7 = p[7 * 64 + tid]; q8 = p[8 * 64 + tid];
            q9 = p[9 * 64 + tid];
            if (tid < 32) qt = conf[(size_t)tn * TDW + 2560 + tid];
        }

        // ---- compute tile t from sb[par] ----
        const float* r = &sb[par][a * 81 + h * 40];   // stride-81: 2-way alias = free
        float x0 = r[0];                 // h=0 lane: class 0
        float s0 = 0.f, s1 = 0.f, s2 = 0.f, s3 = 0.f;
        #pragma unroll
        for (int j = 0; j < 40; j += 4) {
            s0 += __expf(r[j]);
            s1 += __expf(r[j + 1]);
            s2 += __expf(r[j + 2]);
            s3 += __expf(r[j + 3]);
        }
        float s = (s0 + s1) + (s2 + s3) + (float)h * __expf(r[40]);  // h=1 adds cls 80
        s += __shfl_xor(s, 32);          // combine the two half-rows
        float res = __logf(s) - x0;      // valid on h==0 lanes

        if (!more) {
            if (h == 0) sout[(size_t)t * TILE + a] = res;
            break;
        }

        // ds_write of next tile: compiler emits s_waitcnt vmcnt(0) right here,
        // waiting only on the 11 loads above (prev iter's store is long retired).
        {
            float4* lp = (float4*)&sb[par ^ 1][0];
            lp[0 * 64 + tid] = q0; lp[1 * 64 + tid] = q1; lp[2 * 64 + tid] = q2;
            lp[3 * 64 + tid] = q3; lp[4 * 64 + tid] = q4; lp[5 * 64 + tid] = q5;
            lp[6 * 64 + tid] = q6; lp[7 * 64 + tid] = q7; lp[8 * 64 + tid] = q8;
            lp[9 * 64 + tid] = q9;
            if (tid < 32) sb[par ^ 1][2560 + tid] = qt;
        }
        if (h == 0) sout[(size_t)t * TILE + a] = res;   // after ds_write: ack overlaps next iter

        t = tn; par ^= 1;
    }
}

// ---------------- K2: per-batch positives + mining + inline finalize ----------------
#define K2_T 1024
#define VPT 9   // ceil(8732/1024)

__global__ __launch_bounds__(K2_T) void mine_kernel(
    const float* __restrict__ conf, const float* __restrict__ loc,
    const float* __restrict__ tgt, const float* __restrict__ sout,
    double* __restrict__ accum, unsigned long long* __restrict__ hits,
    unsigned int* __restrict__ done, float* __restrict__ out)
{
    __shared__ int   cnt[34];   // slots 0..30: bisect iters, 32: c0, 33: cg
    __shared__ float fs[4];     // 0: sall, 1: sg, 2: pos_ce, 3: pos_loc
    __shared__ int   nm_s;
    int b = blockIdx.x, tid = threadIdx.x, lane = tid & 63;
    if (tid < 34) cnt[tid] = 0;
    if (tid < 4)  fs[tid] = 0.f;
    if (tid == 0) nm_s = 0;
    __syncthreads();

    float v[VPT]; int lab[VPT];
    size_t base = (size_t)b * A_ANCH;
    #pragma unroll
    for (int i = 0; i < VPT; ++i) {
        int idx = tid + i * K2_T;
        bool in = idx < A_ANCH;
        v[i]   = in ? sout[base + idx] : -1.f;
        lab[i] = in ? (int)tgt[(base + idx) * 5 + 4] : 0;
    }

    // ---- positives: CE correction + GIoU; mask out of mining ----
    float pce = 0.f, ploc = 0.f; int pc = 0;
    #pragma unroll
    for (int i = 0; i < VPT; ++i) {
        if (lab[i] > 0) {
            size_t gi = base + (size_t)(tid + i * K2_T);
            float r0 = conf[gi * NCLS];
            float rl = conf[gi * NCLS + lab[i]];
            pce += v[i] + r0 - rl;       // ce = (lse - r0) + r0 - rl
            float4 p = *(const float4*)(loc + gi * 4);
            const float* tg = tgt + gi * 5;
            float tx1 = tg[0], ty1 = tg[1], tx2 = tg[2], ty2 = tg[3];
            float area_p = (p.z - p.x) * (p.w - p.y);
            float area_t = (tx2 - tx1) * (ty2 - ty1);
            float iw = fmaxf(fminf(p.z, tx2) - fmaxf(p.x, tx1), 0.f);
            float ih = fmaxf(fminf(p.w, ty2) - fmaxf(p.y, ty1), 0.f);
            float inter = iw * ih;
            float uni   = area_p + area_t - inter;
            float iou   = inter / (uni + EPSF);
            float cw = fmaxf(p.z, tx2) - fminf(p.x, tx1);
            float ch = fmaxf(p.w, ty2) - fminf(p.y, ty1);
            float area_c = cw * ch;
            ploc += 1.f - (iou - (area_c - uni) / (area_c + EPSF));
            pc++;
            v[i] = -1.f;                 // exclude from mining
        }
    }
    for (int off = 32; off; off >>= 1) {
        pc   += __shfl_xor(pc, off);
        pce  += __shfl_xor(pce, off);
        ploc += __shfl_xor(ploc, off);
    }
    if (lane == 0) {
        if (pc) atomicAdd(&nm_s, pc);
        atomicAdd(&fs[2], pce);
        atomicAdd(&fs[3], ploc);
    }

    // ---- count & sum of all mining candidates (v >= 0) ----
    int c = 0; float sa = 0.f;
    #pragma unroll
    for (int i = 0; i < VPT; ++i) { if (v[i] >= 0.f) { c++; sa += v[i]; } }
    for (int off = 32; off; off >>= 1) { c += __shfl_xor(c, off); sa += __shfl_xor(sa, off); }
    if (lane == 0) { atomicAdd(&cnt[32], c); atomicAdd(&fs[0], sa); }
    __syncthreads();

    int k = 3 * nm_s;
    int c0 = cnt[32]; float sall = fs[0];
    float negl = 0.f;
    if (k >= c0) {
        negl = sall;
    } else if (k > 0) {
        // bisect IEEE bits for the k-th largest candidate (values > 0)
        unsigned lo = 0u, hi = 0x7F800000u;
        int it = 0;
        while (hi - lo > 1u) {           // 31 uniform iterations
            unsigned mid = lo + (hi - lo) / 2u;
            float thr = __uint_as_float(mid);
            int cc = 0;
            #pragma unroll
            for (int i = 0; i < VPT; ++i) cc += (v[i] >= thr) ? 1 : 0;
            for (int off = 32; off; off >>= 1) cc += __shfl_xor(cc, off);
            if (lane == 0) atomicAdd(&cnt[it], cc);
            __syncthreads();
            if (cnt[it] >= k) lo = mid; else hi = mid;
            ++it;
        }
        float tth = __uint_as_float(lo); // exact k-th largest value
        int cg = 0; float sg = 0.f;
        #pragma unroll
        for (int i = 0; i < VPT; ++i) { if (v[i] > tth) { cg++; sg += v[i]; } }
        for (int off = 32; off; off >>= 1) { cg += __shfl_xor(cg, off); sg += __shfl_xor(sg, off); }
        if (lane == 0) { atomicAdd(&cnt[33], cg); atomicAdd(&fs[1], sg); }
        __syncthreads();
        negl = fs[1] + (float)(k - cnt[33]) * tth;   // ties contribute value tth
    }

    // ---- per-batch accumulate; last finished block finalizes ----
    if (tid == 0) {
        atomicAdd(&accum[0], (double)(fs[2] + negl));
        atomicAdd(&accum[1], (double)fs[3]);
        atomicAdd(hits, (unsigned long long)nm_s);
        __threadfence();                 // publish the adds before signaling
        unsigned old = atomicAdd(done, 1u);
        if (old == B_BATCH - 1) {        // all 64 batch blocks have published
            double conf_s = __hip_atomic_load(&accum[0], __ATOMIC_ACQUIRE, __HIP_MEMORY_SCOPE_AGENT);
            double loc_s  = __hip_atomic_load(&accum[1], __ATOMIC_ACQUIRE, __HIP_MEMORY_SCOPE_AGENT);
            unsigned long long h = __hip_atomic_load(hits, __ATOMIC_ACQUIRE, __HIP_MEMORY_SCOPE_AGENT);
            double denom = (double)(h > 0 ? h : 1ull);
            if (h > 0) {
                out[0] = (float)((conf_s + loc_s) / denom);
                out[1] = (float)(conf_s / denom);
                out[2] = (float)(loc_s / denom);
            } else {
                out[0] = 0.f; out[1] = 0.f; out[2] = 0.f;
            }
        }
    }
}

extern "C" void kernel_launch(void* const* d_in, const int* in_sizes, int n_in,
                              void* d_out, int out_size, void* d_ws, size_t ws_size,
                              hipStream_t stream) {
    const float* conf = (const float*)d_in[0];
    const float* loc  = (const float*)d_in[1];
    const float* tgt  = (const float*)d_in[2];
    float* out = (float*)d_out;

    char* ws = (char*)d_ws;
    float* sout = (float*)ws;
    double* accum = (double*)(ws + SBYTES);
    unsigned long long* hits = (unsigned long long*)(ws + SBYTES + 16);
    unsigned int* done = (unsigned int*)(ws + SBYTES + 24);

    lse_kernel<<<dim3(GRID1), dim3(64), 0, stream>>>(conf, sout, accum, hits, done);
    mine_kernel<<<dim3(B_BATCH), dim3(K2_T), 0, stream>>>(
        conf, loc, tgt, sout, accum, hits, done, out);
}

// Round 12
// 50.179 us; speedup vs baseline: 2.1391x; 1.2537x over previous
//
#include <hip/hip_runtime.h>
#include <math.h>

#define NCLS 81
#define A_ANCH 8732
#define B_BATCH 64
#define NANCH (B_BATCH * A_ANCH)   // 558,848 anchors
#define EPSF 1e-7f

// ---- K1 tiling: 32 anchors/tile, register-staged, double-buffered LDS ----
#define TILE 32
#define TDW  (TILE * NCLS)      // 2592 dwords = 10368 B, 16B-aligned per tile
#define BUFDW 2624              // 10*256 + 64 (tail chunk region)
#define NT (NANCH / TILE)       // 17,464 tiles (exact)
#define GRID1 1792              // 7 blocks/CU * 256 CU (2x2624x4 = 21KB LDS/block)

// ---------------- workspace layout ----------------
// [0]      sout : NANCH floats (-logp0 per anchor)
// [SBYTES] accum: 2 doubles | +16 hits(ull) | +24 done-ctr(u32)
static const size_t SBYTES = (size_t)NANCH * sizeof(float);

// ---------------- K1: streaming -logp0 (lse - x0) per anchor ----------------
// [UNCHANGED from R8/R11 — proven best at ~3.7 TB/s read]
__global__ __launch_bounds__(64) void lse_kernel(
    const float* __restrict__ conf, float* __restrict__ sout,
    double* __restrict__ accum, unsigned long long* __restrict__ hits,
    unsigned int* __restrict__ done)
{
    __shared__ float sb[2][BUFDW];   // 20,992 B -> 7 blocks/CU

    int tid = threadIdx.x;
    if (blockIdx.x == 0 && tid == 0) {   // consumers run in the next kernel
        accum[0] = 0.0; accum[1] = 0.0; *hits = 0ull; *done = 0u;
    }

    int a = tid & 31, h = tid >> 5;  // 2 lanes/anchor: h=0 -> cls 0..39, h=1 -> 40..80
    int t = blockIdx.x;

    float4 q0, q1, q2, q3, q4, q5, q6, q7, q8, q9;
    float qt = 0.f;

    // prologue: load tile t -> regs -> LDS[0]
    {
        const float4* p = (const float4*)conf + (size_t)t * (TDW / 4);
        q0 = p[0 * 64 + tid]; q1 = p[1 * 64 + tid]; q2 = p[2 * 64 + tid];
        q3 = p[3 * 64 + tid]; q4 = p[4 * 64 + tid]; q5 = p[5 * 64 + tid];
        q6 = p[6 * 64 + tid]; q7 = p[7 * 64 + tid]; q8 = p[8 * 64 + tid];
        q9 = p[9 * 64 + tid];
        if (tid < 32) qt = conf[(size_t)t * TDW + 2560 + tid];
        float4* lp = (float4*)&sb[0][0];
        lp[0 * 64 + tid] = q0; lp[1 * 64 + tid] = q1; lp[2 * 64 + tid] = q2;
        lp[3 * 64 + tid] = q3; lp[4 * 64 + tid] = q4; lp[5 * 64 + tid] = q5;
        lp[6 * 64 + tid] = q6; lp[7 * 64 + tid] = q7; lp[8 * 64 + tid] = q8;
        lp[9 * 64 + tid] = q9;
        if (tid < 32) sb[0][2560 + tid] = qt;
    }
    int par = 0;

    #pragma clang loop unroll(disable)
    while (true) {
        int tn = t + GRID1;
        bool more = (tn < NT);
        if (more) {   // issue next tile's loads; they fly during the compute below
            const float4* p = (const float4*)conf + (size_t)tn * (TDW / 4);
            q0 = p[0 * 64 + tid]; q1 = p[1 * 64 + tid]; q2 = p[2 * 64 + tid];
            q3 = p[3 * 64 + tid]; q4 = p[4 * 64 + tid]; q5 = p[5 * 64 + tid];
            q6 = p[6 * 64 + tid]; q7 = p[7 * 64 + tid]; q8 = p[8 * 64 + tid];
            q9 = p[9 * 64 + tid];
            if (tid < 32) qt = conf[(size_t)tn * TDW + 2560 + tid];
        }

        // ---- compute tile t from sb[par] ----
        const float* r = &sb[par][a * 81 + h * 40];   // stride-81: 2-way alias = free
        float x0 = r[0];                 // h=0 lane: class 0
        float s0 = 0.f, s1 = 0.f, s2 = 0.f, s3 = 0.f;
        #pragma unroll
        for (int j = 0; j < 40; j += 4) {
            s0 += __expf(r[j]);
            s1 += __expf(r[j + 1]);
            s2 += __expf(r[j + 2]);
            s3 += __expf(r[j + 3]);
        }
        float s = (s0 + s1) + (s2 + s3) + (float)h * __expf(r[40]);  // h=1 adds cls 80
        s += __shfl_xor(s, 32);          // combine the two half-rows
        float res = __logf(s) - x0;      // valid on h==0 lanes

        if (!more) {
            if (h == 0) sout[(size_t)t * TILE + a] = res;
            break;
        }

        {
            float4* lp = (float4*)&sb[par ^ 1][0];
            lp[0 * 64 + tid] = q0; lp[1 * 64 + tid] = q1; lp[2 * 64 + tid] = q2;
            lp[3 * 64 + tid] = q3; lp[4 * 64 + tid] = q4; lp[5 * 64 + tid] = q5;
            lp[6 * 64 + tid] = q6; lp[7 * 64 + tid] = q7; lp[8 * 64 + tid] = q8;
            lp[9 * 64 + tid] = q9;
            if (tid < 32) sb[par ^ 1][2560 + tid] = qt;
        }
        if (h == 0) sout[(size_t)t * TILE + a] = res;

        t = tn; par ^= 1;
    }
}

// ---------------- K2: positives + radix-select mining + inline finalize ----------------
#define K2_T 1024
#define VPT 9       // ceil(8732/1024)
#define NBIN 4096   // 12-bit radix level

__global__ __launch_bounds__(K2_T) void mine_kernel(
    const float* __restrict__ conf, const float* __restrict__ loc,
    const float* __restrict__ tgt, const float* __restrict__ sout,
    double* __restrict__ accum, unsigned long long* __restrict__ hits,
    unsigned int* __restrict__ done, float* __restrict__ out)
{
    __shared__ int   hist[NBIN];   // 16 KB
    __shared__ int   wsum[16];
    __shared__ int   wex[16];      // per-wave exclusive-above partial
    __shared__ int   selB, selCab; // crossing bin + count strictly above it
    __shared__ float fs[4];        // 0: sall, 1: sg, 2: pos_ce, 3: pos_loc
    __shared__ int   c0_s, cg_s, nm_s;

    int b = blockIdx.x, tid = threadIdx.x;
    int lane = tid & 63, wid = tid >> 6;

    for (int i = tid; i < NBIN; i += K2_T) hist[i] = 0;
    if (tid < 4)  fs[tid] = 0.f;
    if (tid == 0) { c0_s = 0; cg_s = 0; nm_s = 0; }
    __syncthreads();

    // ---- load values + labels ----
    float v[VPT]; int lab[VPT];
    size_t base = (size_t)b * A_ANCH;
    #pragma unroll
    for (int i = 0; i < VPT; ++i) {
        int idx = tid + i * K2_T;
        bool in = idx < A_ANCH;
        v[i]   = in ? sout[base + idx] : -1.f;
        lab[i] = in ? (int)tgt[(base + idx) * 5 + 4] : 0;
    }

    // ---- positives: CE correction + GIoU; mask out of mining ----
    float pce = 0.f, ploc = 0.f; int pc = 0;
    #pragma unroll
    for (int i = 0; i < VPT; ++i) {
        if (lab[i] > 0) {
            size_t gi = base + (size_t)(tid + i * K2_T);
            float r0 = conf[gi * NCLS];
            float rl = conf[gi * NCLS + lab[i]];
            pce += v[i] + r0 - rl;       // ce = (lse - r0) + r0 - rl
            float4 p = *(const float4*)(loc + gi * 4);
            const float* tg = tgt + gi * 5;
            float tx1 = tg[0], ty1 = tg[1], tx2 = tg[2], ty2 = tg[3];
            float area_p = (p.z - p.x) * (p.w - p.y);
            float area_t = (tx2 - tx1) * (ty2 - ty1);
            float iw = fmaxf(fminf(p.z, tx2) - fmaxf(p.x, tx1), 0.f);
            float ih = fmaxf(fminf(p.w, ty2) - fmaxf(p.y, ty1), 0.f);
            float inter = iw * ih;
            float uni   = area_p + area_t - inter;
            float iou   = inter / (uni + EPSF);
            float cw = fmaxf(p.z, tx2) - fminf(p.x, tx1);
            float ch = fmaxf(p.w, ty2) - fminf(p.y, ty1);
            float area_c = cw * ch;
            ploc += 1.f - (iou - (area_c - uni) / (area_c + EPSF));
            pc++;
            v[i] = -1.f;                 // exclude from mining
        }
    }
    // candidate count & total sum
    int c = 0; float sa = 0.f;
    #pragma unroll
    for (int i = 0; i < VPT; ++i) { if (v[i] >= 0.f) { c++; sa += v[i]; } }
    for (int off = 32; off; off >>= 1) {
        pc += __shfl_xor(pc, off);  pce += __shfl_xor(pce, off);
        ploc += __shfl_xor(ploc, off);
        c  += __shfl_xor(c, off);   sa  += __shfl_xor(sa, off);
    }
    if (lane == 0) {
        if (pc) atomicAdd(&nm_s, pc);
        atomicAdd(&fs[2], pce);
        atomicAdd(&fs[3], ploc);
        atomicAdd(&c0_s, c);
        atomicAdd(&fs[0], sa);
    }
    __syncthreads();

    int k = 3 * nm_s;
    int c0 = c0_s; float sall = fs[0];
    float negl = 0.f;

    if (k > 0) {
        if (k >= c0) {
            negl = sall;
        } else {
            // ---- 2-level 12-bit radix select for the k-th largest ----
            int B1v = 0, B2v = 0, kk = k;
            for (int lvl = 0; lvl < 2; ++lvl) {
                if (lvl == 1) {   // re-zero histogram for level 2
                    for (int i = tid; i < NBIN; i += K2_T) hist[i] = 0;
                    __syncthreads();
                }
                #pragma unroll
                for (int i = 0; i < VPT; ++i) {
                    if (v[i] >= 0.f) {
                        unsigned bits = __float_as_uint(v[i]);
                        if (lvl == 0) {
                            atomicAdd(&hist[bits >> 19], 1);
                        } else if ((int)(bits >> 19) == B1v) {
                            atomicAdd(&hist[(bits >> 7) & 4095], 1);
                        }
                    }
                }
                __syncthreads();

                // suffix-scan to find crossing bin (bins ascend with value)
                int b0 = tid * 4;
                int h0 = hist[b0], h1 = hist[b0 + 1], h2 = hist[b0 + 2], h3 = hist[b0 + 3];
                int tsum = h0 + h1 + h2 + h3;
                int ssum = tsum;
                #pragma unroll
                for (int off = 1; off < 64; off <<= 1) {
                    int o = __shfl_down(ssum, off);
                    ssum += (lane + off < 64) ? o : 0;
                }
                if (lane == 0) wsum[wid] = ssum;   // wave total
                __syncthreads();
                if (wid == 0) {
                    int wv = (lane < 16) ? wsum[lane] : 0;
                    int ws = wv;
                    #pragma unroll
                    for (int off = 1; off < 64; off <<= 1) {
                        int o = __shfl_down(ws, off);
                        ws += (lane + off < 64) ? o : 0;
                    }
                    if (lane < 16) wex[lane] = ws - wv;   // sum of waves above
                }
                __syncthreads();
                int above = wex[wid] + (ssum - tsum);      // count in bins above my chunk
                if (above < kk && above + tsum >= kk) {    // unique thread
                    int cum = above, B = b0;
                    if      (cum + h3 >= kk) { B = b0 + 3; }
                    else if (cum + h3 + h2 >= kk) { cum += h3; B = b0 + 2; }
                    else if (cum + h3 + h2 + h1 >= kk) { cum += h3 + h2; B = b0 + 1; }
                    else { cum += h3 + h2 + h1; B = b0; }
                    selB = B; selCab = cum;
                }
                __syncthreads();
                if (lvl == 0) { B1v = selB; } else { B2v = selB; }
                kk -= selCab;    // remaining needed within selected bin
                __syncthreads();
            }

            // ---- final sweep against the 24-bit threshold key ----
            unsigned tk = ((unsigned)B1v << 12) | (unsigned)B2v;
            float tval = __uint_as_float(((unsigned)B1v << 19) | ((unsigned)B2v << 7));
            int cg = 0; float sg = 0.f;
            #pragma unroll
            for (int i = 0; i < VPT; ++i) {
                if (v[i] >= 0.f) {
                    unsigned key = __float_as_uint(v[i]) >> 7;
                    if (key > tk) { cg++; sg += v[i]; }
                }
            }
            for (int off = 32; off; off >>= 1) {
                cg += __shfl_xor(cg, off); sg += __shfl_xor(sg, off);
            }
            if (lane == 0) { atomicAdd(&cg_s, cg); atomicAdd(&fs[1], sg); }
            __syncthreads();
            negl = fs[1] + (float)(k - cg_s) * tval;   // ties at t (24-bit exact bin edge)
        }
    }

    // ---- per-batch accumulate; last finished block finalizes ----
    if (tid == 0) {
        atomicAdd(&accum[0], (double)(fs[2] + negl));
        atomicAdd(&accum[1], (double)fs[3]);
        atomicAdd(hits, (unsigned long long)nm_s);
        __threadfence();
        unsigned old = atomicAdd(done, 1u);
        if (old == B_BATCH - 1) {
            double conf_s = __hip_atomic_load(&accum[0], __ATOMIC_ACQUIRE, __HIP_MEMORY_SCOPE_AGENT);
            double loc_s  = __hip_atomic_load(&accum[1], __ATOMIC_ACQUIRE, __HIP_MEMORY_SCOPE_AGENT);
            unsigned long long h = __hip_atomic_load(hits, __ATOMIC_ACQUIRE, __HIP_MEMORY_SCOPE_AGENT);
            double denom = (double)(h > 0 ? h : 1ull);
            if (h > 0) {
                out[0] = (float)((conf_s + loc_s) / denom);
                out[1] = (float)(conf_s / denom);
                out[2] = (float)(loc_s / denom);
            } else {
                out[0] = 0.f; out[1] = 0.f; out[2] = 0.f;
            }
        }
    }
}

extern "C" void kernel_launch(void* const* d_in, const int* in_sizes, int n_in,
                              void* d_out, int out_size, void* d_ws, size_t ws_size,
                              hipStream_t stream) {
    const float* conf = (const float*)d_in[0];
    const float* loc  = (const float*)d_in[1];
    const float* tgt  = (const float*)d_in[2];
    float* out = (float*)d_out;

    char* ws = (char*)d_ws;
    float* sout = (float*)ws;
    double* accum = (double*)(ws + SBYTES);
    unsigned long long* hits = (unsigned long long*)(ws + SBYTES + 16);
    unsigned int* done = (unsigned int*)(ws + SBYTES + 24);

    lse_kernel<<<dim3(GRID1), dim3(64), 0, stream>>>(conf, sout, accum, hits, done);
    mine_kernel<<<dim3(B_BATCH), dim3(K2_T), 0, stream>>>(
        conf, loc, tgt, sout, accum, hits, done, out);
}

// Round 13
// 50.150 us; speedup vs baseline: 2.1404x; 1.0006x over previous
//
#include <hip/hip_runtime.h>
#include <math.h>

#define NCLS 81
#define A_ANCH 8732
#define B_BATCH 64
#define NANCH (B_BATCH * A_ANCH)   // 558,848 anchors
#define EPSF 1e-7f

// ---- K1: register-only lse. 4 anchors = 81 float4 exactly; 8 lanes/octet ----
#define GROUPS (NANCH / 32)     // 17,464 groups of 32 anchors (exact)
#define LBLK 256
#define LGRID 2183              // 2183*4 = 8732 waves -> exactly 2 groups/wave
#define NWAVE (LGRID * 4)

// ---------------- workspace layout ----------------
// [0]      sout : NANCH floats (-logp0 per anchor)
// [SBYTES] accum: 2 doubles | +16 hits(ull) | +24 done-ctr(u32)
static const size_t SBYTES = (size_t)NANCH * sizeof(float);

#define ACC_ADD(KK, val) do {            \
    if      ((KK) == 0) a0 += (val);     \
    else if ((KK) == 1) a1 += (val);     \
    else if ((KK) == 2) a2 += (val);     \
    else                a3 += (val);     \
} while (0)

// one element: e = 32r + 4j + c, anchor_local = e/81. Window over j is 28 wide
// (< 81) so it crosses at most one anchor boundary -> K, T compile-time.
#define PROC(r, c, comp) do {                              \
    const int lo = 32 * (r) + (c);                         \
    const int K  = lo / 81;                                \
    const int K2 = (lo + 28) / 81;                         \
    float ev = __expf(comp);                               \
    if (K == K2) { ACC_ADD(K, ev); }                       \
    else {                                                 \
        const int T = (81 * (K + 1) - lo + 3) / 4;         \
        float hv = (j >= T) ? ev : 0.f;                    \
        ACC_ADD(K, ev - hv); ACC_ADD(K + 1, hv);           \
    }                                                      \
} while (0)

#define PROCQ(r, qv) do {        \
    PROC(r, 0, (qv).x);          \
    PROC(r, 1, (qv).y);          \
    PROC(r, 2, (qv).z);          \
    PROC(r, 3, (qv).w);          \
} while (0)

// ---------------- K1: streaming -logp0, zero LDS, all-register ----------------
// Per wave-iteration: 32 anchors. 11 coalesced float4 rounds (8x128B runs per
// instr = 16 cache lines, same as contiguous), compile-time segmented reduce
// into 4 accumulators, 12 intra-octet shuffles, one strided x0 load (L1-hit),
// 32 contiguous result stores. No LDS, no barriers, no manual waitcnt.
__global__ __launch_bounds__(LBLK) void lse_kernel(
    const float* __restrict__ conf, float* __restrict__ sout,
    double* __restrict__ accum, unsigned long long* __restrict__ hits,
    unsigned int* __restrict__ done)
{
    int tid = threadIdx.x;
    if (blockIdx.x == 0 && tid == 0) {   // consumers run in the next kernel
        accum[0] = 0.0; accum[1] = 0.0; *hits = 0ull; *done = 0u;
    }
    int w = blockIdx.x * 4 + (tid >> 6);
    int lane = tid & 63;
    int o = lane >> 3, j = lane & 7;     // octet id, lane-in-octet

    #pragma clang loop unroll(disable)
    for (int g = w; g < GROUPS; g += NWAVE) {
        const float4* p = (const float4*)conf + (size_t)g * 648 + o * 81 + j;
        float4 q0 = p[0],  q1 = p[8],  q2 = p[16], q3 = p[24], q4 = p[32];
        float4 q5 = p[40], q6 = p[48], q7 = p[56], q8 = p[64], q9 = p[72];
        float4 q10 = make_float4(-INFINITY, -INFINITY, -INFINITY, -INFINITY);
        if (j == 0) q10 = p[80];         // slot 80: only j==0 is in-octet
        float x0 = 0.f;
        if (j < 4) x0 = conf[(size_t)g * 2592 + (o * 4 + j) * 81];  // class-0 logit

        float a0 = 0.f, a1 = 0.f, a2 = 0.f, a3 = 0.f;
        PROCQ(0, q0); PROCQ(1, q1); PROCQ(2, q2); PROCQ(3, q3); PROCQ(4, q4);
        PROCQ(5, q5); PROCQ(6, q6); PROCQ(7, q7); PROCQ(8, q8); PROCQ(9, q9);
        // r=10: elements 320..323 all map to anchor 3; j>0 lanes hold -inf -> 0
        a3 += __expf(q10.x); a3 += __expf(q10.y);
        a3 += __expf(q10.z); a3 += __expf(q10.w);

        // intra-octet butterfly: all 8 lanes get all 4 anchor sums
        #pragma unroll
        for (int d = 1; d < 8; d <<= 1) {
            a0 += __shfl_xor(a0, d); a1 += __shfl_xor(a1, d);
            a2 += __shfl_xor(a2, d); a3 += __shfl_xor(a3, d);
        }
        if (j < 4) {
            float m = (j == 0) ? a0 : (j == 1) ? a1 : (j == 2) ? a2 : a3;
            sout[(size_t)g * 32 + o * 4 + j] = __logf(m) - x0;   // -logp0 > 0
        }
    }
}

// ---------------- K2: positives + radix-select mining + inline finalize ----------------
// [UNCHANGED from R12]
#define K2_T 1024
#define VPT 9       // ceil(8732/1024)
#define NBIN 4096   // 12-bit radix level

__global__ __launch_bounds__(K2_T) void mine_kernel(
    const float* __restrict__ conf, const float* __restrict__ loc,
    const float* __restrict__ tgt, const float* __restrict__ sout,
    double* __restrict__ accum, unsigned long long* __restrict__ hits,
    unsigned int* __restrict__ done, float* __restrict__ out)
{
    __shared__ int   hist[NBIN];   // 16 KB
    __shared__ int   wsum[16];
    __shared__ int   wex[16];      // per-wave exclusive-above partial
    __shared__ int   selB, selCab; // crossing bin + count strictly above it
    __shared__ float fs[4];        // 0: sall, 1: sg, 2: pos_ce, 3: pos_loc
    __shared__ int   c0_s, cg_s, nm_s;

    int b = blockIdx.x, tid = threadIdx.x;
    int lane = tid & 63, wid = tid >> 6;

    for (int i = tid; i < NBIN; i += K2_T) hist[i] = 0;
    if (tid < 4)  fs[tid] = 0.f;
    if (tid == 0) { c0_s = 0; cg_s = 0; nm_s = 0; }
    __syncthreads();

    // ---- load values + labels ----
    float v[VPT]; int lab[VPT];
    size_t base = (size_t)b * A_ANCH;
    #pragma unroll
    for (int i = 0; i < VPT; ++i) {
        int idx = tid + i * K2_T;
        bool in = idx < A_ANCH;
        v[i]   = in ? sout[base + idx] : -1.f;
        lab[i] = in ? (int)tgt[(base + idx) * 5 + 4] : 0;
    }

    // ---- positives: CE correction + GIoU; mask out of mining ----
    float pce = 0.f, ploc = 0.f; int pc = 0;
    #pragma unroll
    for (int i = 0; i < VPT; ++i) {
        if (lab[i] > 0) {
            size_t gi = base + (size_t)(tid + i * K2_T);
            float r0 = conf[gi * NCLS];
            float rl = conf[gi * NCLS + lab[i]];
            pce += v[i] + r0 - rl;       // ce = (lse - r0) + r0 - rl
            float4 p = *(const float4*)(loc + gi * 4);
            const float* tg = tgt + gi * 5;
            float tx1 = tg[0], ty1 = tg[1], tx2 = tg[2], ty2 = tg[3];
            float area_p = (p.z - p.x) * (p.w - p.y);
            float area_t = (tx2 - tx1) * (ty2 - ty1);
            float iw = fmaxf(fminf(p.z, tx2) - fmaxf(p.x, tx1), 0.f);
            float ih = fmaxf(fminf(p.w, ty2) - fmaxf(p.y, ty1), 0.f);
            float inter = iw * ih;
            float uni   = area_p + area_t - inter;
            float iou   = inter / (uni + EPSF);
            float cw = fmaxf(p.z, tx2) - fminf(p.x, tx1);
            float ch = fmaxf(p.w, ty2) - fminf(p.y, ty1);
            float area_c = cw * ch;
            ploc += 1.f - (iou - (area_c - uni) / (area_c + EPSF));
            pc++;
            v[i] = -1.f;                 // exclude from mining
        }
    }
    // candidate count & total sum
    int c = 0; float sa = 0.f;
    #pragma unroll
    for (int i = 0; i < VPT; ++i) { if (v[i] >= 0.f) { c++; sa += v[i]; } }
    for (int off = 32; off; off >>= 1) {
        pc += __shfl_xor(pc, off);  pce += __shfl_xor(pce, off);
        ploc += __shfl_xor(ploc, off);
        c  += __shfl_xor(c, off);   sa  += __shfl_xor(sa, off);
    }
    if (lane == 0) {
        if (pc) atomicAdd(&nm_s, pc);
        atomicAdd(&fs[2], pce);
        atomicAdd(&fs[3], ploc);
        atomicAdd(&c0_s, c);
        atomicAdd(&fs[0], sa);
    }
    __syncthreads();

    int k = 3 * nm_s;
    int c0 = c0_s; float sall = fs[0];
    float negl = 0.f;

    if (k > 0) {
        if (k >= c0) {
            negl = sall;
        } else {
            // ---- 2-level 12-bit radix select for the k-th largest ----
            int B1v = 0, B2v = 0, kk = k;
            for (int lvl = 0; lvl < 2; ++lvl) {
                if (lvl == 1) {   // re-zero histogram for level 2
                    for (int i = tid; i < NBIN; i += K2_T) hist[i] = 0;
                    __syncthreads();
                }
                #pragma unroll
                for (int i = 0; i < VPT; ++i) {
                    if (v[i] >= 0.f) {
                        unsigned bits = __float_as_uint(v[i]);
                        if (lvl == 0) {
                            atomicAdd(&hist[bits >> 19], 1);
                        } else if ((int)(bits >> 19) == B1v) {
                            atomicAdd(&hist[(bits >> 7) & 4095], 1);
                        }
                    }
                }
                __syncthreads();

                // suffix-scan to find crossing bin (bins ascend with value)
                int b0 = tid * 4;
                int h0 = hist[b0], h1 = hist[b0 + 1], h2 = hist[b0 + 2], h3 = hist[b0 + 3];
                int tsum = h0 + h1 + h2 + h3;
                int ssum = tsum;
                #pragma unroll
                for (int off = 1; off < 64; off <<= 1) {
                    int oo = __shfl_down(ssum, off);
                    ssum += (lane + off < 64) ? oo : 0;
                }
                if (lane == 0) wsum[wid] = ssum;   // wave total
                __syncthreads();
                if (wid == 0) {
                    int wv = (lane < 16) ? wsum[lane] : 0;
                    int ws = wv;
                    #pragma unroll
                    for (int off = 1; off < 64; off <<= 1) {
                        int oo = __shfl_down(ws, off);
                        ws += (lane + off < 64) ? oo : 0;
                    }
                    if (lane < 16) wex[lane] = ws - wv;   // sum of waves above
                }
                __syncthreads();
                int above = wex[wid] + (ssum - tsum);      // count in bins above my chunk
                if (above < kk && above + tsum >= kk) {    // unique thread
                    int cum = above, B = b0;
                    if      (cum + h3 >= kk) { B = b0 + 3; }
                    else if (cum + h3 + h2 >= kk) { cum += h3; B = b0 + 2; }
                    else if (cum + h3 + h2 + h1 >= kk) { cum += h3 + h2; B = b0 + 1; }
                    else { cum += h3 + h2 + h1; B = b0; }
                    selB = B; selCab = cum;
                }
                __syncthreads();
                if (lvl == 0) { B1v = selB; } else { B2v = selB; }
                kk -= selCab;    // remaining needed within selected bin
                __syncthreads();
            }

            // ---- final sweep against the 24-bit threshold key ----
            unsigned tk = ((unsigned)B1v << 12) | (unsigned)B2v;
            float tval = __uint_as_float(((unsigned)B1v << 19) | ((unsigned)B2v << 7));
            int cg = 0; float sg = 0.f;
            #pragma unroll
            for (int i = 0; i < VPT; ++i) {
                if (v[i] >= 0.f) {
                    unsigned key = __float_as_uint(v[i]) >> 7;
                    if (key > tk) { cg++; sg += v[i]; }
                }
            }
            for (int off = 32; off; off >>= 1) {
                cg += __shfl_xor(cg, off); sg += __shfl_xor(sg, off);
            }
            if (lane == 0) { atomicAdd(&cg_s, cg); atomicAdd(&fs[1], sg); }
            __syncthreads();
            negl = fs[1] + (float)(k - cg_s) * tval;   // ties at bin edge (24-bit exact)
        }
    }

    // ---- per-batch accumulate; last finished block finalizes ----
    if (tid == 0) {
        atomicAdd(&accum[0], (double)(fs[2] + negl));
        atomicAdd(&accum[1], (double)fs[3]);
        atomicAdd(hits, (unsigned long long)nm_s);
        __threadfence();
        unsigned old = atomicAdd(done, 1u);
        if (old == B_BATCH - 1) {
            double conf_s = __hip_atomic_load(&accum[0], __ATOMIC_ACQUIRE, __HIP_MEMORY_SCOPE_AGENT);
            double loc_s  = __hip_atomic_load(&accum[1], __ATOMIC_ACQUIRE, __HIP_MEMORY_SCOPE_AGENT);
            unsigned long long h = __hip_atomic_load(hits, __ATOMIC_ACQUIRE, __HIP_MEMORY_SCOPE_AGENT);
            double denom = (double)(h > 0 ? h : 1ull);
            if (h > 0) {
                out[0] = (float)((conf_s + loc_s) / denom);
                out[1] = (float)(conf_s / denom);
                out[2] = (float)(loc_s / denom);
            } else {
                out[0] = 0.f; out[1] = 0.f; out[2] = 0.f;
            }
        }
    }
}

extern "C" void kernel_launch(void* const* d_in, const int* in_sizes, int n_in,
                              void* d_out, int out_size, void* d_ws, size_t ws_size,
                              hipStream_t stream) {
    const float* conf = (const float*)d_in[0];
    const float* loc  = (const float*)d_in[1];
    const float* tgt  = (const float*)d_in[2];
    float* out = (float*)d_out;

    char* ws = (char*)d_ws;
    float* sout = (float*)ws;
    double* accum = (double*)(ws + SBYTES);
    unsigned long long* hits = (unsigned long long*)(ws + SBYTES + 16);
    unsigned int* done = (unsigned int*)(ws + SBYTES + 24);

    lse_kernel<<<dim3(LGRID), dim3(LBLK), 0, stream>>>(conf, sout, accum, hits, done);
    mine_kernel<<<dim3(B_BATCH), dim3(K2_T), 0, stream>>>(
        conf, loc, tgt, sout, accum, hits, done, out);
}